// Round 13
// baseline (254.933 us; speedup 1.0000x reference)
//
#include <hip/hip_runtime.h>
#include <hip/hip_bf16.h>

#define BB 4
#define CC 256
#define CHH 128
#define NN 4096
#define KSHIFT 12.0f

typedef __attribute__((ext_vector_type(8))) short bf16x8;
typedef __attribute__((ext_vector_type(4))) float f32x4;

__device__ __forceinline__ float to_f(float v) { return v; }
__device__ __forceinline__ float to_f(__hip_bfloat16 v) { return __bfloat162float(v); }
__device__ __forceinline__ void st_f(float* p, float v) { *p = v; }
__device__ __forceinline__ void st_f(__hip_bfloat16* p, float v) { *p = __float2bfloat16(v); }
__device__ __forceinline__ unsigned short f2bf(float f) {
    __hip_bfloat16 h = __float2bfloat16(f);
    unsigned short u;
    __builtin_memcpy(&u, &h, 2);
    return u;
}
__device__ __forceinline__ bf16x8 ldb8(const unsigned short* p) { return *(const bf16x8*)p; }

// wire-dtype-generic 8-elem bf16 fragment load (inline conversion for fp32).
__device__ __forceinline__ bf16x8 ld_bf8(const __hip_bfloat16* p) {
    return ldb8((const unsigned short*)p);
}
__device__ __forceinline__ bf16x8 ld_bf8(const float* p) {
    float4 a = *(const float4*)p;
    float4 c = *(const float4*)(p + 4);
    union { bf16x8 v; unsigned short u[8]; } r;
    r.u[0] = f2bf(a.x); r.u[1] = f2bf(a.y); r.u[2] = f2bf(a.z); r.u[3] = f2bf(a.w);
    r.u[4] = f2bf(c.x); r.u[5] = f2bf(c.y); r.u[6] = f2bf(c.z); r.u[7] = f2bf(c.w);
    return r.v;
}

// async global->LDS, 16 B per lane (proven rounds 8-12).
__device__ __forceinline__ void gload_lds16(const unsigned short* g, unsigned short* l) {
    __builtin_amdgcn_global_load_lds(
        (const __attribute__((address_space(1))) unsigned int*)g,
        (__attribute__((address_space(3))) unsigned int*)l, 16, 0, 0);
}

// In-kernel wire-dtype detect (proven logic rounds 3-12), lane0 + broadcast.
__device__ __forceinline__ int detect_wire(const void* tb) {
    int f = 0;
    if ((threadIdx.x & 63) == 0) {
        const __hip_bfloat16* p = (const __hip_bfloat16*)tb;
        int big = 0, zeros = 0;
        for (int i = 0; i < 128; ++i) {
            float v = __bfloat162float(p[i]);
            if (!(fabsf(v) <= 0.5f)) big = 1;
            if ((i & 1) == 0 && v == 0.0f) zeros++;
        }
        f = (big || zeros >= 32) ? 1 : 0;
    }
    return __shfl(f, 0, 64);
}

// ---------------------------------------------------------------------------
// Kernel 1: fused x-transpose + weight-convert + three 1x1 convs via MFMA.
// Replaces round-12's detect + prep + xtrans + conv3 (4 launches -> 1).
//   Stage x[all c][16 p] transposed+converted into swizzled LDS; W fragments
//   and biases converted inline from wire dtype.
//   cv=0 theta -> T1b natural; cv=1 phi -> T2t via shfl transpose (audited
//   round 12); cv=2 g -> T3b natural (X3t scatter can't fuse — round-11 bug).
// ---------------------------------------------------------------------------
template <typename T>
__device__ __forceinline__ void conv3_body(const T* __restrict__ x,
                                           const T* __restrict__ tw, const T* __restrict__ tb2,
                                           const T* __restrict__ fw, const T* __restrict__ fb,
                                           const T* __restrict__ gw, const T* __restrict__ gb,
                                           unsigned short* __restrict__ T1b,
                                           unsigned short* __restrict__ T2t,
                                           unsigned short* __restrict__ T3b,
                                           unsigned short* tx) {
    int b = blockIdx.y;
    int p0 = blockIdx.x * 16;
    int flat = threadIdx.x;
    int w = flat >> 6, lane = flat & 63, m = lane & 15, quad = lane >> 4;
    const T* xb = x + (size_t)b * CC * NN;
#pragma unroll
    for (int pass = 0; pass < 16; ++pass) {   // stage x-tile transposed, swizzled
        int idx = pass * 256 + flat;
        int c = idx >> 4, p = idx & 15;
        int ch = (c >> 3) ^ (p & 7);
        tx[p * 256 + ch * 8 + (c & 7)] = f2bf(to_f(xb[(size_t)c * NN + p0 + p]));
    }
    __syncthreads();
    bf16x8 xf[8];
#pragma unroll
    for (int kc = 0; kc < 8; ++kc) {
        int ch = (kc * 4 + quad) ^ (m & 7);
        xf[kc] = *(const bf16x8*)&tx[m * 256 + ch * 8];
    }
    unsigned short* t1  = T1b + (size_t)b * CHH * NN;
    unsigned short* t2t = T2t + (size_t)b * CHH * NN;   // [p][o], row stride 128
    unsigned short* t3  = T3b + (size_t)b * CHH * NN;   // natural (CH,N)
    const T* wsrcs[3] = {tw, fw, gw};
    const T* bsrcs[3] = {tb2, fb, gb};
#pragma unroll
    for (int q = 0; q < 6; ++q) {
        int t = w * 6 + q;
        int cv = t >> 3, ot = t & 7;
        int o0 = ot * 16;
        const T* wrow = wsrcs[cv] + (size_t)(o0 + m) * CC;
        f32x4 acc = {0.f, 0.f, 0.f, 0.f};
#pragma unroll
        for (int kc = 0; kc < 8; ++kc) {
            bf16x8 wf = ld_bf8(&wrow[kc * 32 + quad * 8]);
            acc = __builtin_amdgcn_mfma_f32_16x16x32_bf16(wf, xf[kc], acc, 0, 0, 0);
        }
        unsigned short hv[4];
#pragma unroll
        for (int r = 0; r < 4; ++r)
            hv[r] = f2bf(acc[r] + to_f(bsrcs[cv][o0 + quad * 4 + r]));
        if (cv == 1) {
            unsigned int lo = (unsigned int)hv[0] | ((unsigned int)hv[1] << 16);
            unsigned int hi = (unsigned int)hv[2] | ((unsigned int)hv[3] << 16);
            int src = (lane & 3) * 16 + (lane >> 2);
            unsigned int tlo = (unsigned int)__shfl((int)lo, src, 64);
            unsigned int thi = (unsigned int)__shfl((int)hi, src, 64);
            unsigned int* dst = (unsigned int*)&t2t[(size_t)(p0 + (lane >> 2)) * CHH +
                                                    o0 + (lane & 3) * 4];
            dst[0] = tlo;
            dst[1] = thi;
        } else {
            unsigned short* outp = (cv == 0) ? t1 : t3;
#pragma unroll
            for (int r = 0; r < 4; ++r)
                outp[(size_t)(o0 + quad * 4 + r) * NN + p0 + m] = hv[r];
        }
    }
}

__launch_bounds__(256)
__global__ void conv3_mfma_kernel(const void* x,
                                  const void* tw, const void* tb2, const void* fw,
                                  const void* fb, const void* gw, const void* gb,
                                  unsigned short* __restrict__ T1b,
                                  unsigned short* __restrict__ T2t,
                                  unsigned short* __restrict__ T3b) {
    __shared__ __align__(16) unsigned short tx[16 * 256];  // swizzled x-tile
    int flag = detect_wire(tb2);
    if (flag)
        conv3_body<float>((const float*)x, (const float*)tw, (const float*)tb2,
                          (const float*)fw, (const float*)fb, (const float*)gw,
                          (const float*)gb, T1b, T2t, T3b, tx);
    else
        conv3_body<__hip_bfloat16>((const __hip_bfloat16*)x, (const __hip_bfloat16*)tw,
                                   (const __hip_bfloat16*)tb2, (const __hip_bfloat16*)fw,
                                   (const __hip_bfloat16*)fb, (const __hip_bfloat16*)gw,
                                   (const __hip_bfloat16*)gb, T1b, T2t, T3b, tx);
}

// ---------------------------------------------------------------------------
// Kernel 2: stats (blocks 0..2047) + X3t transpose (blocks 2048..2559) merged.
// Stats: proven round-10/12 machinery, i-split 16 (grid 2048 = 8 blocks/CU).
// Transpose: proven tiled transpose of the g-view (N,CH) -> X3t[j][u].
// ---------------------------------------------------------------------------
__launch_bounds__(256)
__global__ void statstrans_kernel(const unsigned short* __restrict__ T1b,
                                  const unsigned short* __restrict__ T2t,
                                  const unsigned short* __restrict__ T3b,
                                  unsigned short* __restrict__ X3t,
                                  float* __restrict__ Lpart) {
    __shared__ __align__(16) char smem[16384];
    int blk = blockIdx.x;
    int flat = threadIdx.x;
    if (blk < 2048) {
        unsigned short* th = (unsigned short*)smem;   // theta tile, swizzled
        int b = (blk & 7) >> 1;
        int rest = (blk >> 3) * 2 + (blk & 1);        // 0..511 = strip*16 + iq
        int strip = rest >> 4, iq = rest & 15;
        int ibase = iq * 256;
        int w = flat >> 6, lane = flat & 63, m = lane & 15, quad = lane >> 4;
        const unsigned short* A  = T1b + (size_t)b * CHH * NN;
        const unsigned short* Bt = T2t + (size_t)b * CHH * NN;
        int u0w = strip * 128 + w * 32;               // this wave's 32-u window
        bf16x8 bfr[2][4];
#pragma unroll
        for (int g = 0; g < 2; ++g)
#pragma unroll
            for (int kc = 0; kc < 4; ++kc)
                bfr[g][kc] = ldb8(&Bt[(size_t)(u0w + g * 16 + m) * CHH + kc * 32 + quad * 8]);
        float csum[2] = {0.f, 0.f};
        for (int t = 0; t < 4; ++t) {                 // 4 i-tiles of 64 in this chunk
            int i0t = ibase + t * 64;
            __syncthreads();
#pragma unroll
            for (int i = 0; i < 4; ++i) {
                int sl = i * 256 + flat;
                int r = sl >> 4, ch = sl & 15;
                int c = ch ^ (r & 7);
                gload_lds16(&A[(size_t)(i0t + r) * CHH + c * 8], &th[sl * 8]);
            }
            __syncthreads();
#pragma unroll
            for (int s = 0; s < 4; ++s) {
                int irow = s * 16 + m;
                bf16x8 af[4];
#pragma unroll
                for (int kc = 0; kc < 4; ++kc) {
                    int ch = (kc * 4 + quad) ^ (irow & 7);
                    af[kc] = *(const bf16x8*)&th[irow * 128 + ch * 8];
                }
#pragma unroll
                for (int g = 0; g < 2; ++g) {
                    f32x4 acc = {0.f, 0.f, 0.f, 0.f};
#pragma unroll
                    for (int kc = 0; kc < 4; ++kc)
                        acc = __builtin_amdgcn_mfma_f32_16x16x32_bf16(af[kc], bfr[g][kc],
                                                                      acc, 0, 0, 0);
#pragma unroll
                    for (int r = 0; r < 4; ++r)
                        csum[g] += __expf(acc[r] - KSHIFT);
                }
            }
        }
#pragma unroll
        for (int g = 0; g < 2; ++g) {
            csum[g] += __shfl_xor(csum[g], 16, 64);
            csum[g] += __shfl_xor(csum[g], 32, 64);
            if (lane < 16)
                Lpart[((size_t)iq * BB + b) * NN + u0w + g * 16 + m] = csum[g];
        }
    } else {
        // X3t transpose: in = g-view (R=NN, C=CHH) row-major, out (C, R).
        unsigned short (*t)[68] = (unsigned short (*)[68])smem;
        int blk2 = blk - 2048;                        // 0..511
        int b = blk2 & 3;
        int idx = blk2 >> 2;                          // 0..127
        int c0 = (idx & 1) * 64, r0 = (idx >> 1) * 64;
        const unsigned short* in = T3b + (size_t)b * CHH * NN;
        unsigned short* out = X3t + (size_t)b * CHH * NN;
#pragma unroll
        for (int tt = 0; tt < 16; ++tt) {
            int id = flat + tt * 256;
            int r = id >> 6, c = id & 63;
            t[c][r] = in[(size_t)(r0 + r) * CHH + c0 + c];
        }
        __syncthreads();
#pragma unroll
        for (int tt = 0; tt < 16; ++tt) {
            int id = flat + tt * 256;
            int c = id >> 6, r = id & 63;
            out[(size_t)(c0 + c) * NN + r0 + r] = t[c][r];
        }
    }
}

// ---------------------------------------------------------------------------
// Kernel 3 (pass B): Y = P @ X3 — UNCHANGED round-12 structure (57 µs,
// 24% MfmaUtil) except the LL prologue now sums 16 Lpart chunks.
// ---------------------------------------------------------------------------
__launch_bounds__(256)
__global__ void attn_mfma_kernel(const unsigned short* __restrict__ T1b,
                                 const unsigned short* __restrict__ T2t,
                                 const unsigned short* __restrict__ X3t,
                                 const float* __restrict__ Lpart,
                                 unsigned short* __restrict__ Yp0,
                                 unsigned short* __restrict__ Yp1,
                                 unsigned short* __restrict__ Yp2,
                                 unsigned short* __restrict__ Yp3) {
    int blk = blockIdx.x;
    int b = (blk & 7) >> 1;
    int rest = (blk >> 3) * 2 + (blk & 1);   // 0..127 = it*4 + uc
    int it = rest >> 2, uc = rest & 3;
    int i0 = it * 128;
    unsigned short* Yp = uc == 0 ? Yp0 : (uc == 1 ? Yp1 : (uc == 2 ? Yp2 : Yp3));
    int flat = threadIdx.x;
    int w = flat >> 6, lane = flat & 63, m = lane & 15, quad = lane >> 4;
    const unsigned short* A  = T1b + (size_t)b * CHH * NN;
    const unsigned short* Bt = T2t + (size_t)b * CHH * NN;
    const unsigned short* X3 = X3t + (size_t)b * CHH * NN;

    __shared__ unsigned short bt[64 * 128];
    __shared__ unsigned short x3[128 * 64];
    __shared__ unsigned short pT[4][2][16][40];
    __shared__ float llh[1024];

    int ubeg = uc * 1024;
#pragma unroll
    for (int k = 0; k < 4; ++k) {             // LL prologue (16 Lpart chunks)
        int idx = k * 256 + flat;
        int u = ubeg + idx;
        float s = 0.f;
#pragma unroll
        for (int c = 0; c < 16; ++c)
            s += Lpart[((size_t)c * BB + b) * NN + u];
        llh[idx] = logf(s) + KSHIFT;
    }

    int iw = i0 + w * 32;
    bf16x8 ath[2][4];
#pragma unroll
    for (int g = 0; g < 2; ++g)
#pragma unroll
        for (int kc = 0; kc < 4; ++kc)
            ath[g][kc] = ldb8(&A[(size_t)(iw + g * 16 + m) * CHH + kc * 32 + quad * 8]);
    f32x4 yacc[2][8];
#pragma unroll
    for (int g = 0; g < 2; ++g)
#pragma unroll
        for (int js = 0; js < 8; ++js) yacc[g][js] = (f32x4){0.f, 0.f, 0.f, 0.f};

    for (int u0 = ubeg; u0 < ubeg + 1024; u0 += 64) {
        __syncthreads();
#pragma unroll
        for (int i = 0; i < 4; ++i) {         // stage Bt tile (16 KB)
            int sl = i * 256 + flat;
            int u = sl >> 4, ch = sl & 15;
            int c = ch ^ (u & 7);
            gload_lds16(&Bt[(size_t)(u0 + u) * CHH + c * 8], &bt[sl * 8]);
        }
#pragma unroll
        for (int i = 0; i < 4; ++i) {         // stage X3 tile (16 KB)
            int sl = i * 256 + flat;
            int j = sl >> 3, ch = sl & 7;
            int c = ch ^ (j & 7);
            gload_lds16(&X3[(size_t)j * NN + u0 + c * 8], &x3[sl * 8]);
        }
        __syncthreads();
#pragma unroll
        for (int h = 0; h < 2; ++h) {
#pragma unroll
            for (int su = 0; su < 2; ++su) {
                int u = h * 32 + su * 16 + m;
                f32x4 a0 = {0.f, 0.f, 0.f, 0.f}, a1 = {0.f, 0.f, 0.f, 0.f};
#pragma unroll
                for (int kc = 0; kc < 4; ++kc) {
                    int ch = (kc * 4 + quad) ^ (u & 7);
                    bf16x8 bf = *(const bf16x8*)&bt[u * 128 + ch * 8];
                    a0 = __builtin_amdgcn_mfma_f32_16x16x32_bf16(ath[0][kc], bf, a0, 0, 0, 0);
                    a1 = __builtin_amdgcn_mfma_f32_16x16x32_bf16(ath[1][kc], bf, a1, 0, 0, 0);
                }
                float ll = llh[u0 - ubeg + u];
#pragma unroll
                for (int r = 0; r < 4; ++r) {
                    pT[w][0][quad * 4 + r][su * 16 + m] = f2bf(__expf(a0[r] - ll));
                    pT[w][1][quad * 4 + r][su * 16 + m] = f2bf(__expf(a1[r] - ll));
                }
            }
            bf16x8 pa0 = *(const bf16x8*)&pT[w][0][m][quad * 8];
            bf16x8 pa1 = *(const bf16x8*)&pT[w][1][m][quad * 8];
#pragma unroll
            for (int js = 0; js < 8; ++js) {
                int j = js * 16 + m;
                int ch = (h * 4 + quad) ^ (j & 7);
                bf16x8 xb = *(const bf16x8*)&x3[j * 64 + ch * 8];
                yacc[0][js] = __builtin_amdgcn_mfma_f32_16x16x32_bf16(pa0, xb, yacc[0][js], 0, 0, 0);
                yacc[1][js] = __builtin_amdgcn_mfma_f32_16x16x32_bf16(pa1, xb, yacc[1][js], 0, 0, 0);
            }
        }
    }
#pragma unroll
    for (int g = 0; g < 2; ++g)
#pragma unroll
        for (int js = 0; js < 8; ++js)
#pragma unroll
            for (int r = 0; r < 4; ++r)
                Yp[((size_t)b * NN + iw + g * 16 + quad * 4 + r) * CHH + js * 16 + m] =
                    f2bf(yacc[g][js][r]);
}

// ---------------------------------------------------------------------------
// Kernel 4: out = x + out_w @ (Yp0+Yp1+Yp2+Yp3)^T + out_b via MFMA.
// OW/bias converted inline from wire dtype (prep kernel deleted).
// ---------------------------------------------------------------------------
template <typename T>
__device__ __forceinline__ void outconv_body(const T* __restrict__ x,
                                             const unsigned short* __restrict__ Yp0,
                                             const unsigned short* __restrict__ Yp1,
                                             const unsigned short* __restrict__ Yp2,
                                             const unsigned short* __restrict__ Yp3,
                                             const T* __restrict__ ow,
                                             const T* __restrict__ ob,
                                             T* __restrict__ out) {
    int b = blockIdx.y;
    int p0 = blockIdx.x * 16;
    int flat = threadIdx.x;
    int w = flat >> 6, lane = flat & 63, m = lane & 15, quad = lane >> 4;
    size_t yoff = ((size_t)b * NN + p0 + m) * CHH;
    const unsigned short* yrows[4] = {Yp0 + yoff, Yp1 + yoff, Yp2 + yoff, Yp3 + yoff};
    bf16x8 yf[4][4];
#pragma unroll
    for (int pz = 0; pz < 4; ++pz)
#pragma unroll
        for (int kc = 0; kc < 4; ++kc)
            yf[pz][kc] = ldb8(&yrows[pz][kc * 32 + quad * 8]);
#pragma unroll
    for (int q = 0; q < 4; ++q) {
        int o0 = (w * 4 + q) * 16;
        const T* wrow = ow + (size_t)(o0 + m) * CHH;
        f32x4 acc = {0.f, 0.f, 0.f, 0.f};
#pragma unroll
        for (int kc = 0; kc < 4; ++kc) {
            bf16x8 aw = ld_bf8(&wrow[kc * 32 + quad * 8]);
#pragma unroll
            for (int pz = 0; pz < 4; ++pz)
                acc = __builtin_amdgcn_mfma_f32_16x16x32_bf16(aw, yf[pz][kc], acc, 0, 0, 0);
        }
#pragma unroll
        for (int r = 0; r < 4; ++r) {
            int co = o0 + quad * 4 + r;
            size_t oi = ((size_t)b * CC + co) * NN + p0 + m;
            st_f(&out[oi], acc[r] + to_f(ob[co]) + to_f(x[oi]));
        }
    }
}

__launch_bounds__(256)
__global__ void outconv_mfma_kernel(const void* x,
                                    const unsigned short* __restrict__ Yp0,
                                    const unsigned short* __restrict__ Yp1,
                                    const unsigned short* __restrict__ Yp2,
                                    const unsigned short* __restrict__ Yp3,
                                    const void* ow, const void* ob, const void* tb2,
                                    void* out) {
    int flag = detect_wire(tb2);
    if (flag)
        outconv_body<float>((const float*)x, Yp0, Yp1, Yp2, Yp3,
                            (const float*)ow, (const float*)ob, (float*)out);
    else
        outconv_body<__hip_bfloat16>((const __hip_bfloat16*)x, Yp0, Yp1, Yp2, Yp3,
                                     (const __hip_bfloat16*)ow, (const __hip_bfloat16*)ob,
                                     (__hip_bfloat16*)out);
}

extern "C" void kernel_launch(void* const* d_in, const int* in_sizes, int n_in,
                              void* d_out, int out_size, void* d_ws, size_t ws_size,
                              hipStream_t stream) {
    const void* x  = d_in[0];
    const void* tw = d_in[1];
    const void* tb = d_in[2];
    const void* fw = d_in[3];
    const void* fb = d_in[4];
    const void* gw = d_in[5];
    const void* gb = d_in[6];
    const void* ow = d_in[7];
    const void* ob = d_in[8];

    // Workspace (~30.4 MB): 7 bf16 TE buffers + Lpart. Yp2 aliases T3b
    // (dead after the merged kernel's transpose part).
    const size_t TE = (size_t)BB * CHH * NN;        // 2,097,152
    unsigned short* T1b = (unsigned short*)d_ws;
    unsigned short* T2t = T1b + TE;                 // phi transposed [p][o]
    unsigned short* X3t = T2t + TE;                 // g-view transposed [j][u]
    unsigned short* T3b = X3t + TE;                 // g natural (CH,N)
    unsigned short* Yp0 = T3b + TE;                 // fresh
    unsigned short* Yp1 = Yp0 + TE;                 // fresh
    unsigned short* Yp3 = Yp1 + TE;                 // fresh
    unsigned short* Yp2 = T3b;                      // alias (dead after transpose)
    float* Lpart = (float*)(Yp3 + TE);              // 16 * BB * NN = 262144 floats

    conv3_mfma_kernel<<<dim3(NN / 16, BB), 256, 0, stream>>>(
        x, tw, tb, fw, fb, gw, gb, T1b, T2t, T3b);
    statstrans_kernel<<<dim3(2560), 256, 0, stream>>>(T1b, T2t, T3b, X3t, Lpart);
    attn_mfma_kernel<<<dim3(512), 256, 0, stream>>>(T1b, T2t, X3t, Lpart, Yp0, Yp1, Yp2, Yp3);
    outconv_mfma_kernel<<<dim3(NN / 16, BB), 256, 0, stream>>>(x, Yp0, Yp1, Yp2, Yp3,
                                                               ow, ob, tb, d_out);
}